// Round 11
// baseline (646.988 us; speedup 1.0000x reference)
//
#include <hip/hip_runtime.h>
#include <hip/hip_bf16.h>

#define NT 4           // node types (labels)
#define FEAT 256       // nfeat == nhid
#define OUT3 64        // nclass
#define NPW 8          // nodes per wave in eighth-split aggregation

typedef __bf16 bf16x8 __attribute__((ext_vector_type(8)));
typedef float  f32x4  __attribute__((ext_vector_type(4)));
typedef unsigned int u32x2 __attribute__((ext_vector_type(2)));

__device__ inline unsigned int f2bf_bits(float f) {
    __hip_bfloat16 h = __float2bfloat16(f);   // RNE
    unsigned short u;
    __builtin_memcpy(&u, &h, 2);
    return (unsigned int)u;
}
__device__ inline float bfl(unsigned int u) { return __uint_as_float(u << 16); }
__device__ inline float bfh(unsigned int u) { return __uint_as_float(u & 0xffff0000u); }
// stored feature pos p (pi order) -> natural feature index, within each 64-block
__device__ __host__ inline int nat_of(int p) {
    int lo = p & 63;
    return (p & ~63) | (((lo & 3) << 4) | (lo >> 2));
}

// ---------------- pass A: dst-bucket histogram (dst>>8) + label histogram ----------------
__global__ __launch_bounds__(512) void pass_a(const int* __restrict__ dst,
                                              const int* __restrict__ labels,
                                              int* __restrict__ bcnt, int* __restrict__ lc,
                                              int E, int N) {
    __shared__ int h[256];
    __shared__ int lh[NT];
    int tid = threadIdx.x;
    if (tid < 256) h[tid] = 0;
    if (tid < NT) lh[tid] = 0;
    __syncthreads();
    int base = blockIdx.x * 4096;
#pragma unroll
    for (int k = 0; k < 8; ++k) {
        int e = base + k * 512 + tid;
        if (e < E) atomicAdd(&h[((unsigned)dst[e]) >> 8], 1);
    }
#pragma unroll
    for (int k = 0; k < 8; ++k) {
        int i = base + k * 512 + tid;
        if (i < N) atomicAdd(&lh[labels[i]], 1);
    }
    __syncthreads();
    if (tid < 256) { int v = h[tid]; if (v) atomicAdd(&bcnt[tid], v); }
    if (tid < NT) { int v = lh[tid]; if (v) atomicAdd(&lc[tid], v); }
}

// ------- scan buckets -> boff/gcur, rowoff[N]=E; label starts (pad 64) -------
__global__ __launch_bounds__(256) void scan_master(
    const int* __restrict__ bcnt, const int* __restrict__ lc,
    int* __restrict__ boff, int* __restrict__ gcur, int* __restrict__ rowoff,
    int* __restrict__ lstart, int NB, int N, int E) {
    __shared__ int s[256];
    int tid = threadIdx.x;
    int own = (tid < NB) ? bcnt[tid] : 0;
    s[tid] = own;
    __syncthreads();
    for (int d = 1; d < 256; d <<= 1) {
        int v = (tid >= d) ? s[tid - d] : 0;
        __syncthreads();
        s[tid] += v;
        __syncthreads();
    }
    int excl = s[tid] - own;
    if (tid < NB) { boff[tid] = excl; gcur[tid] = excl; }
    if (tid == 0) {
        boff[NB] = E; rowoff[N] = E;
        int run = 0;
        for (int l = 0; l < NT; ++l) {
            lstart[l] = run;
            run += (lc[l] + 63) & ~63;
        }
    }
}

// ------- node scatter: build iperm (orig -> label-sorted slot) -------
__global__ void scatter_nodes(const int* __restrict__ labels, const int* __restrict__ lstart,
                              int* __restrict__ lcur, int* __restrict__ iperm, int N) {
    int n = blockIdx.x * 256 + threadIdx.x;
    int lab = (n < N) ? labels[n] : -1;
    int lane = threadIdx.x & 63;
    for (int l = 0; l < NT; ++l) {
        unsigned long long m = __ballot(lab == l);
        if (m == 0ull) continue;
        int leader = __builtin_ctzll(m);
        int base = 0;
        if (lane == leader) base = atomicAdd(&lcur[l], (int)__popcll(m));
        base = __shfl(base, leader, 64);
        if (lab == l) {
            int prefix = (int)__popcll(m & ((1ull << lane) - 1ull));
            iperm[n] = lstart[l] + base + prefix;
        }
    }
}

// ================= FUSE_A: scatter_edges + cast_x + cast_w_all =================
// seg 0 [0, nbEB): edge scatter into bucket regions; earr rec: x = slot|(dst&255)<<16, y = w
// seg 1 [nbEB, nbEB+nbX): cast x -> bf16 eighth-major slot rows act8[8][slot][32]
// seg 2 rest: cast W1/W2/W3 -> swizzled bf16 + permuted biases
__global__ __launch_bounds__(512) void fuse_a(
    const int* __restrict__ src, const int* __restrict__ dst, const float* __restrict__ w,
    const int* __restrict__ iperm, int* __restrict__ gcur, uint2* __restrict__ earr, int E,
    const float* __restrict__ x, unsigned short* __restrict__ act8, size_t ES, int total4,
    const float* __restrict__ W1, const float* __restrict__ W2, const float* __restrict__ W3,
    const float* __restrict__ b1, const float* __restrict__ b2,
    unsigned short* __restrict__ W1b, unsigned short* __restrict__ W2b,
    unsigned short* __restrict__ W3b, float* __restrict__ biasPerm,
    int nbEB, int nbX) {
    int tid = threadIdx.x;
    int blk = (int)blockIdx.x;
    if (blk < nbEB) {
        // ---- edge scatter ----
        __shared__ int h[256];
        __shared__ int basearr[256];
        if (tid < 256) h[tid] = 0;
        __syncthreads();
        int base = blk * 4096;
        int b[8], rank[8], px[8]; float wv[8];
#pragma unroll
        for (int k = 0; k < 8; ++k) {
            int e = base + k * 512 + tid;
            if (e < E) {
                int d = dst[e];
                b[k] = ((unsigned)d) >> 8;
                px[k] = iperm[src[e]] | ((d & 255) << 16);
                wv[k] = w[e];
                rank[k] = atomicAdd(&h[b[k]], 1);
            } else b[k] = -1;
        }
        __syncthreads();
        if (tid < 256) { int c = h[tid]; basearr[tid] = c ? atomicAdd(&gcur[tid], c) : 0; }
        __syncthreads();
#pragma unroll
        for (int k = 0; k < 8; ++k) {
            if (b[k] >= 0) {
                int pos = basearr[b[k]] + rank[k];
                earr[pos] = make_uint2((unsigned)px[k], __float_as_uint(wv[k]));
            }
        }
    } else if (blk < nbEB + nbX) {
        // ---- cast x: float4 group i covers stored pos 4i..4i+3 -> eighth (i&63)>>3 ----
        int i = (blk - nbEB) * 512 + tid;
        if (i < total4) {
            float4 v = ((const float4*)x)[i];
            unsigned int lo = f2bf_bits(v.x) | (f2bf_bits(v.y) << 16);
            unsigned int hi = f2bf_bits(v.z) | (f2bf_bits(v.w) << 16);
            int slot = iperm[i >> 6];
            int pg = i & 63;
            ((uint2*)(act8 + (size_t)(pg >> 3) * ES))[(size_t)slot * 8 + (pg & 7)] =
                make_uint2(lo, hi);
        }
    } else {
        // ---- cast W + biases ----
        const int S = NT * FEAT * FEAT;
        const int S3 = NT * FEAT * OUT3;
        int idx = (blk - nbEB - nbX) * 512 + tid;
        if (idx < 2 * S + S3) {
            const float* W; unsigned short* D; int OUTF; int t; bool remap;
            if (idx < S)          { W = W1; D = W1b; OUTF = FEAT; t = idx;         remap = false; }
            else if (idx < 2 * S) { W = W2; D = W2b; OUTF = FEAT; t = idx - S;     remap = true; }
            else                  { W = W3; D = W3b; OUTF = OUT3; t = idx - 2 * S; remap = true; }
            int n = t % OUTF;
            int r = t / OUTF;              // lab*256 + k_slot
            int j = r & 7, q = (r >> 3) & 3, k0 = (r >> 5) & 7, lab = r >> 8;
            int k_slot = k0 * 32 + q * 8 + j;
            int k_src = remap ? nat_of(k_slot) : k_slot;
            float f = W[((size_t)(lab * FEAT + k_src)) * OUTF + n];
            D[(((size_t)lab * 8 + k0) * OUTF + n) * 32 + q * 8 + j] = (unsigned short)f2bf_bits(f);
        } else {
            int p2 = idx - (2 * S + S3);
            if (p2 < 256) biasPerm[p2] = b1[nat_of(p2)];
            else if (p2 < 512) biasPerm[p2] = b2[nat_of(p2 - 256)];
        }
    }
}

// ------- bucket sort body (256 thr): within-bucket counting sort -> rowoff + edata -------
// final record: (w_bf16 << 16) | src_slot  (proven R3 form, 256-bin)
__device__ void bucket_sort_body(int b, const uint2* __restrict__ earr,
                                 const int* __restrict__ boff, int* __restrict__ rowoff,
                                 unsigned int* __restrict__ edata, int N) {
    int s = boff[b], e = boff[b + 1];
    __shared__ int cnt[256], off[256];
    int tid = threadIdx.x;
    cnt[tid] = 0;
    __syncthreads();
    for (int i = s + tid; i < e; i += 256) atomicAdd(&cnt[(earr[i].x >> 16) & 255], 1);
    __syncthreads();
    off[tid] = cnt[tid];
    __syncthreads();
    for (int d = 1; d < 256; d <<= 1) {
        int v = (tid >= d) ? off[tid - d] : 0;
        __syncthreads();
        off[tid] += v;
        __syncthreads();
    }
    int excl = off[tid] - cnt[tid];
    int node = b * 256 + tid;
    if (node < N) rowoff[node] = s + excl;
    off[tid] = excl;
    __syncthreads();
    for (int i = s + tid; i < e; i += 256) {
        uint2 r = earr[i];
        int d = (r.x >> 16) & 255;
        int k = atomicAdd(&off[d], 1);
        edata[s + k] = (f2bf_bits(__uint_as_float(r.y)) << 16) | (r.x & 0xffff);
    }
}

// ------- proj 256-out body: dense 64 slots x 256 outs per block, eighth-major I/O -------
__device__ void proj256_body(int gb,
                             const unsigned short* __restrict__ act8,
                             const unsigned short* __restrict__ Wswz,
                             const int* __restrict__ lstart,
                             unsigned short* __restrict__ sup8, size_t ES) {
    int warp = threadIdx.x >> 6;
    int lane = threadIdx.x & 63;
    int m0 = gb * 64;
    int lab = (m0 >= lstart[1]) + (m0 >= lstart[2]) + (m0 >= lstart[3]);
    int q = lane >> 4, c = lane & 15;
    int n0 = warp * 64;

    const unsigned short* bb = Wswz + (size_t)lab * FEAT * 256 + (size_t)(n0 + c) * 32 + q * 8;

    f32x4 acc[4][4] = {};
#pragma unroll
    for (int k0 = 0; k0 < 8; ++k0) {
        // A-operand pos p = (k0<4?0:128) + (k0&3)*32 + q*8  ->  eighth e8, offset q*8
        int e8 = ((k0 < 4) ? 0 : 4) + (k0 & 3);
        const unsigned short* ab = act8 + (size_t)e8 * ES + (size_t)(m0 + c) * 32 + q * 8;
        bf16x8 a[4];
#pragma unroll
        for (int t = 0; t < 4; ++t) a[t] = *(const bf16x8*)(ab + (size_t)t * 512);
        const unsigned short* bk = bb + (size_t)k0 * 32 * 256;
#pragma unroll
        for (int u = 0; u < 4; ++u) {
            bf16x8 bfrag = *(const bf16x8*)(bk + u * 512);
#pragma unroll
            for (int t = 0; t < 4; ++t)
                acc[t][u] = __builtin_amdgcn_mfma_f32_16x16x32_bf16(a[t], bfrag, acc[t][u], 0, 0, 0);
        }
    }
    // pi-store: row = m0+t*16+q*4+r ; lane writes pos p = n0 + c*4 + u
    // -> eighth (n0>>5)+(c>>3), uint2 idx row*8 + (c&7)
    uint2* ov = (uint2*)(sup8 + (size_t)((n0 >> 5) + (c >> 3)) * ES);
    int cix = c & 7;
#pragma unroll
    for (int t = 0; t < 4; ++t) {
#pragma unroll
        for (int r = 0; r < 4; ++r) {
            int row = m0 + t * 16 + q * 4 + r;
            unsigned int lo = f2bf_bits(acc[t][0][r]) | (f2bf_bits(acc[t][1][r]) << 16);
            unsigned int hi = f2bf_bits(acc[t][2][r]) | (f2bf_bits(acc[t][3][r]) << 16);
            ov[(size_t)row * 8 + cix] = make_uint2(lo, hi);
        }
    }
}

// ================= FUSE_B: bucket_sort (blocks [0,NB)) + proj256 L1 (rest) =================
__global__ __launch_bounds__(256) void fuse_b(
    const uint2* __restrict__ earr, const int* __restrict__ boff,
    int* __restrict__ rowoff, unsigned int* __restrict__ edata, int N, int NB,
    const unsigned short* __restrict__ act8,
    const unsigned short* __restrict__ Wswz, const int* __restrict__ lstart,
    unsigned short* __restrict__ sup8, size_t ES) {
    int blk = (int)blockIdx.x;
    if (blk < NB) bucket_sort_body(blk, earr, boff, rowoff, edata, N);
    else proj256_body(blk - NB, act8, Wswz, lstart, sup8, ES);
}

// ---------------- standalone proj 256 (layer 2) ----------------
__global__ __launch_bounds__(256) void proj256_kernel(
    const unsigned short* __restrict__ act8,
    const unsigned short* __restrict__ Wswz, const int* __restrict__ lstart,
    unsigned short* __restrict__ sup8, size_t ES) {
    proj256_body((int)blockIdx.x, act8, Wswz, lstart, sup8, ES);
}

// ---------------- proj 64-out: dense 64 slots x 64 outs per block, eighth-major input ----
__global__ __launch_bounds__(256) void proj64_kernel(
    const unsigned short* __restrict__ act8, size_t ES,
    const unsigned short* __restrict__ Wswz, const int* __restrict__ lstart,
    unsigned short* __restrict__ outp) {
    int warp = threadIdx.x >> 6;
    int lane = threadIdx.x & 63;
    int m0 = blockIdx.x * 64;
    int lab = (m0 >= lstart[1]) + (m0 >= lstart[2]) + (m0 >= lstart[3]);
    int q = lane >> 4, c = lane & 15;
    int mb = m0 + warp * 16;

    const unsigned short* bb = Wswz + (size_t)lab * FEAT * OUT3 + (size_t)c * 32 + q * 8;

    f32x4 acc[4] = {};
#pragma unroll
    for (int k0 = 0; k0 < 8; ++k0) {
        int e8 = ((k0 < 4) ? 0 : 4) + (k0 & 3);
        bf16x8 a = *(const bf16x8*)(act8 + (size_t)e8 * ES + (size_t)(mb + c) * 32 + q * 8);
        const unsigned short* bk = bb + (size_t)k0 * 32 * OUT3;
#pragma unroll
        for (int u = 0; u < 4; ++u) {
            bf16x8 bfrag = *(const bf16x8*)(bk + u * 512);
            acc[u] = __builtin_amdgcn_mfma_f32_16x16x32_bf16(a, bfrag, acc[u], 0, 0, 0);
        }
    }
    uint2* ov = (uint2*)outp;
#pragma unroll
    for (int r = 0; r < 4; ++r) {
        int row = mb + q * 4 + r;
        unsigned int lo = f2bf_bits(acc[0][r]) | (f2bf_bits(acc[1][r]) << 16);
        unsigned int hi = f2bf_bits(acc[2][r]) | (f2bf_bits(acc[3][r]) << 16);
        ov[(size_t)row * 16 + c] = make_uint2(lo, hi);
    }
}

// ------- EIGHTH-SPLIT aggregation: blk&7 = feature-eighth = XCD (round-robin) -------
// Stationary 3.2MB eighth-table per XCD. R11: (a) edata reads are NONTEMPORAL so the
// 6.4MB stream doesn't evict the table from L2 (R10's hidden defect: 3.2+6.4 > 4MiB);
// (b) explicit 2-deep software pipeline over 16-edge stages (no sched_barriers) so
// stage k+1's edata+gathers issue under stage k's FMAs -> 32 edges in flight/wave.
__global__ __launch_bounds__(256) void agg8_kernel(
    const unsigned short* __restrict__ sup8, const int* __restrict__ rowoff,
    const unsigned int* __restrict__ edata, const int* __restrict__ iperm,
    const float* __restrict__ biasPerm, int bOff,
    unsigned short* __restrict__ act8out, size_t ES, int N) {
    int blk = (int)blockIdx.x;
    int eighth = blk & 7;
    int warp = __builtin_amdgcn_readfirstlane((int)(threadIdx.x >> 6));
    int wid = (blk >> 3) * 4 + warp;
    int n0 = wid * NPW;
    if (n0 >= N) return;
    int lane = threadIdx.x & 63;
    int eg = lane >> 3;          // edge index within 8-edge batch
    int c  = lane & 7;           // feat chunk (4 feats = uint2)
    const uint2* supE = (const uint2*)(sup8 + (size_t)eighth * ES);
    uint2* ovE = (uint2*)(act8out + (size_t)eighth * ES);
    float4 bv = ((const float4*)(biasPerm + bOff))[eighth * 8 + c];
#pragma unroll
    for (int t = 0; t < NPW; ++t) {
        int n = n0 + t;
        if (n >= N) break;
        int s = __builtin_amdgcn_readfirstlane(rowoff[n]);
        int e = __builtin_amdgcn_readfirstlane(rowoff[n + 1]);
        float a0 = 0.f, a1 = 0.f, a2 = 0.f, a3 = 0.f;
        int j = s;
        // ---- 2-deep pipeline, 16-edge stages ----
        unsigned int eA0 = 0, eA1 = 0; uint2 vA0, vA1;
        bool haveA = (j + 16 <= e);
        if (haveA) {
            eA0 = __builtin_nontemporal_load(&edata[j + eg]);
            eA1 = __builtin_nontemporal_load(&edata[j + 8 + eg]);
            vA0 = supE[(size_t)(eA0 & 0xffffu) * 8 + c];
            vA1 = supE[(size_t)(eA1 & 0xffffu) * 8 + c];
        }
        for (; j + 32 <= e; j += 16) {
            unsigned int eB0 = __builtin_nontemporal_load(&edata[j + 16 + eg]);
            unsigned int eB1 = __builtin_nontemporal_load(&edata[j + 24 + eg]);
            uint2 vB0 = supE[(size_t)(eB0 & 0xffffu) * 8 + c];
            uint2 vB1 = supE[(size_t)(eB1 & 0xffffu) * 8 + c];
            float w0 = __uint_as_float(eA0 & 0xffff0000u);
            float w1 = __uint_as_float(eA1 & 0xffff0000u);
            a0 += w0 * bfl(vA0.x); a1 += w0 * bfh(vA0.x);
            a2 += w0 * bfl(vA0.y); a3 += w0 * bfh(vA0.y);
            a0 += w1 * bfl(vA1.x); a1 += w1 * bfh(vA1.x);
            a2 += w1 * bfl(vA1.y); a3 += w1 * bfh(vA1.y);
            eA0 = eB0; eA1 = eB1; vA0 = vB0; vA1 = vB1;
        }
        if (haveA) {
            float w0 = __uint_as_float(eA0 & 0xffff0000u);
            float w1 = __uint_as_float(eA1 & 0xffff0000u);
            a0 += w0 * bfl(vA0.x); a1 += w0 * bfh(vA0.x);
            a2 += w0 * bfl(vA0.y); a3 += w0 * bfh(vA0.y);
            a0 += w1 * bfl(vA1.x); a1 += w1 * bfh(vA1.x);
            a2 += w1 * bfl(vA1.y); a3 += w1 * bfh(vA1.y);
            j += 16;
        }
        for (; j + 8 <= e; j += 8) {
            unsigned int ed = __builtin_nontemporal_load(&edata[j + eg]);
            uint2 v = supE[(size_t)(ed & 0xffffu) * 8 + c];
            float w = __uint_as_float(ed & 0xffff0000u);
            a0 += w * bfl(v.x); a1 += w * bfh(v.x); a2 += w * bfl(v.y); a3 += w * bfh(v.y);
        }
        if (j < e) {                     // masked batch (<=7 real edges)
            int jj = j + eg;
            int jc = (jj < e) ? jj : e - 1;
            unsigned int ed = __builtin_nontemporal_load(&edata[jc]);
            uint2 v = supE[(size_t)(ed & 0xffffu) * 8 + c];
            float w = (jj < e) ? __uint_as_float(ed & 0xffff0000u) : 0.f;
            a0 += w * bfl(v.x); a1 += w * bfh(v.x); a2 += w * bfl(v.y); a3 += w * bfh(v.y);
        }
        // fold the 8 edge-groups (lanes differ in bits 3..5)
#pragma unroll
        for (int m = 8; m <= 32; m <<= 1) {
            a0 += __shfl_xor(a0, m, 64);
            a1 += __shfl_xor(a1, m, 64);
            a2 += __shfl_xor(a2, m, 64);
            a3 += __shfl_xor(a3, m, 64);
        }
        float r0 = fmaxf(a0 + bv.x, 0.f);
        float r1 = fmaxf(a1 + bv.y, 0.f);
        float r2 = fmaxf(a2 + bv.z, 0.f);
        float r3 = fmaxf(a3 + bv.w, 0.f);
        int slot = __builtin_amdgcn_readfirstlane(iperm[n]);
        if (lane < 8) {                  // lanes 0..7 hold chunks 0..7
            u32x2 o;
            o[0] = f2bf_bits(r0) | (f2bf_bits(r1) << 16);
            o[1] = f2bf_bits(r2) | (f2bf_bits(r3) << 16);
            __builtin_nontemporal_store(o, (u32x2*)&ovE[(size_t)slot * 8 + lane]);
        }
    }
}

// ---------------- aggregation, 64-feat: one wave per node (lane = stored pos), fp32 out --
__global__ __launch_bounds__(256) void agg64_kernel(
    const unsigned short* __restrict__ sup, const int* __restrict__ rowoff,
    const unsigned int* __restrict__ edata, const float* __restrict__ b3,
    float* __restrict__ outp, int N) {
    int warp = __builtin_amdgcn_readfirstlane((int)(threadIdx.x >> 6));
    int node = (int)blockIdx.x * 4 + warp;
    if (node >= N) return;
    int lane = threadIdx.x & 63;
    int s = __builtin_amdgcn_readfirstlane(rowoff[node]);
    int e = __builtin_amdgcn_readfirstlane(rowoff[node + 1]);
    float a = 0.f;
    int j = s;
    for (; j + 16 <= e; j += 16) {
        unsigned int ed[16]; unsigned short v[16];
#pragma unroll
        for (int u = 0; u < 16; ++u) ed[u] = edata[j + u];
#pragma unroll
        for (int u = 0; u < 16; ++u) v[u] = sup[(size_t)(ed[u] & 0xffff) * 64 + lane];
#pragma unroll
        for (int u = 0; u < 16; ++u)
            a += __uint_as_float(ed[u] & 0xffff0000u) * __uint_as_float((unsigned int)v[u] << 16);
    }
    if (j < e) {
        unsigned int ed[16]; float wm[16]; unsigned short v[16];
#pragma unroll
        for (int u = 0; u < 16; ++u) {
            int jj = j + u;
            int jc = (jj < e) ? jj : e - 1;
            ed[u] = edata[jc];
            wm[u] = (jj < e) ? __uint_as_float(ed[u] & 0xffff0000u) : 0.f;
        }
#pragma unroll
        for (int u = 0; u < 16; ++u) v[u] = sup[(size_t)(ed[u] & 0xffff) * 64 + lane];
#pragma unroll
        for (int u = 0; u < 16; ++u)
            a += wm[u] * __uint_as_float((unsigned int)v[u] << 16);
    }
    int natp = (((lane & 3) << 4) | (lane >> 2));    // un-permute pi within the 64 outs
    outp[(size_t)node * 64 + natp] = a + b3[natp];
}

extern "C" void kernel_launch(void* const* d_in, const int* in_sizes, int n_in,
                              void* d_out, int out_size, void* d_ws, size_t ws_size,
                              hipStream_t stream) {
    const float* x        = (const float*)d_in[0];
    const int*   edge_src = (const int*)d_in[1];
    const int*   edge_dst = (const int*)d_in[2];
    const float* edge_w   = (const float*)d_in[3];
    const int*   labels   = (const int*)d_in[4];
    const float* W1 = (const float*)d_in[5];
    const float* b1 = (const float*)d_in[6];
    const float* W2 = (const float*)d_in[7];
    const float* b2 = (const float*)d_in[8];
    const float* W3 = (const float*)d_in[9];
    const float* b3 = (const float*)d_in[10];

    const int N = in_sizes[0] / FEAT;
    const int E = in_sizes[1];
    const int NB = (N + 255) >> 8;                    // dst buckets (orig id space)
    const int G64 = (N + NT * 64 + 63) / 64;          // slot-space 64-row tiles (upper bound)
    const int slotCap = G64 * 64;
    const size_t ES = (size_t)slotCap * 32;           // ushorts per feature-eighth table

    // ---- workspace carve (256B aligned) ----
    char* p = (char*)d_ws;
    auto alloc = [&](size_t bytes) -> char* {
        char* r = p;
        p += (bytes + 255) & ~(size_t)255;
        return r;
    };
    unsigned short* bufA = (unsigned short*)alloc((size_t)slotCap * FEAT * 2);
    unsigned short* bufB = (unsigned short*)alloc((size_t)slotCap * FEAT * 2);
    unsigned short* W1b  = (unsigned short*)alloc((size_t)NT * FEAT * FEAT * 2);
    unsigned short* W2b  = (unsigned short*)alloc((size_t)NT * FEAT * FEAT * 2);
    unsigned short* W3b  = (unsigned short*)alloc((size_t)NT * FEAT * OUT3 * 2);
    float*        biasPerm = (float*)alloc(512 * 4);
    int*          rowoff = (int*)alloc((size_t)(N + 1) * 4);
    unsigned int* edata  = (unsigned int*)alloc((size_t)E * 4);
    int*          iperm  = (int*)alloc((size_t)N * 4);
    int*          counters = (int*)alloc(264 * 4);    // bcnt[256] + lc[4] + lcur[4]
    int*          boff   = (int*)alloc(257 * 4);
    int*          gcur   = (int*)alloc(256 * 4);
    int*          lstart = (int*)alloc(64);
    int* bcnt = counters;
    int* lc   = counters + 256;
    int* lcur = counters + 260;

    // eighth-major bf16 tables [8][slotCap][32]: act8 (layer input), sup8 (proj output)
    unsigned short* act8 = bufA;
    unsigned short* sup8 = bufB;
    // raw edge staging ALIASED onto d_out (N*OUT3*4 = 12.8MB = E*8; d_out written
    // only by the final agg64, and earr is fully overwritten by scatter before reads)
    uint2* earr = (uint2*)d_out;

    const int nbEB = (E + 4095) / 4096;
    const int total4 = N * 64;                        // float4 groups in x
    const int nbX = (total4 + 511) / 512;
    const int totW = 2 * NT * FEAT * FEAT + NT * FEAT * OUT3 + 512;
    const int nbW = (totW + 511) / 512;

    // ---- CSR build + label-sort + casts ----
    hipMemsetAsync(counters, 0, 264 * 4, stream);
    pass_a<<<nbEB, 512, 0, stream>>>(edge_dst, labels, bcnt, lc, E, N);
    scan_master<<<1, 256, 0, stream>>>(bcnt, lc, boff, gcur, rowoff, lstart, NB, N, E);
    scatter_nodes<<<(N + 255) / 256, 256, 0, stream>>>(labels, lstart, lcur, iperm, N);
    fuse_a<<<nbEB + nbX + nbW, 512, 0, stream>>>(
        edge_src, edge_dst, edge_w, iperm, gcur, earr, E,
        x, act8, ES, total4,
        W1, W2, W3, b1, b2, W1b, W2b, W3b, biasPerm, nbEB, nbX);

    const int nodeBlk = ((N + NPW - 1) / NPW + 3) / 4;   // blocks per eighth-class
    const int aggGrid = (N + 3) / 4;
    // ---- layer 1 (dst sort overlapped with proj256-L1) ----
    fuse_b<<<NB + G64, 256, 0, stream>>>(earr, boff, rowoff, edata, N, NB,
                                         act8, W1b, lstart, sup8, ES);
    agg8_kernel<<<8 * nodeBlk, 256, 0, stream>>>(sup8, rowoff, edata, iperm,
                                                 biasPerm, 0, act8, ES, N);
    // ---- layer 2 ----
    proj256_kernel<<<G64, 256, 0, stream>>>(act8, W2b, lstart, sup8, ES);
    agg8_kernel<<<8 * nodeBlk, 256, 0, stream>>>(sup8, rowoff, edata, iperm,
                                                 biasPerm, 256, act8, ES, N);
    // ---- layer 3 ----
    proj64_kernel<<<G64, 256, 0, stream>>>(act8, ES, W3b, lstart, bufB);
    agg64_kernel<<<aggGrid, 256, 0, stream>>>(bufB, rowoff, edata, b3, (float*)d_out, N);
}

// Round 12
// 474.955 us; speedup vs baseline: 1.3622x; 1.3622x over previous
//
#include <hip/hip_runtime.h>
#include <hip/hip_bf16.h>

#define NT 4           // node types (labels)
#define FEAT 256       // nfeat == nhid
#define OUT3 64        // nclass

typedef __bf16 bf16x8 __attribute__((ext_vector_type(8)));
typedef float  f32x4  __attribute__((ext_vector_type(4)));

__device__ inline unsigned int f2bf_bits(float f) {
    __hip_bfloat16 h = __float2bfloat16(f);   // RNE
    unsigned short u;
    __builtin_memcpy(&u, &h, 2);
    return (unsigned int)u;
}
__device__ inline float bfl(unsigned int u) { return __uint_as_float(u << 16); }
__device__ inline float bfh(unsigned int u) { return __uint_as_float(u & 0xffff0000u); }
// stored feature pos p (pi order) -> natural feature index, within each 64-block
__device__ __host__ inline int nat_of(int p) {
    int lo = p & 63;
    return (p & ~63) | (((lo & 3) << 4) | (lo >> 2));
}

// ---------------- pass A: dst-bucket histogram (dst>>8) + label histogram ----------------
__global__ __launch_bounds__(512) void pass_a(const int* __restrict__ dst,
                                              const int* __restrict__ labels,
                                              int* __restrict__ bcnt, int* __restrict__ lc,
                                              int E, int N) {
    __shared__ int h[256];
    __shared__ int lh[NT];
    int tid = threadIdx.x;
    if (tid < 256) h[tid] = 0;
    if (tid < NT) lh[tid] = 0;
    __syncthreads();
    int base = blockIdx.x * 4096;
#pragma unroll
    for (int k = 0; k < 8; ++k) {
        int e = base + k * 512 + tid;
        if (e < E) atomicAdd(&h[((unsigned)dst[e]) >> 8], 1);
    }
#pragma unroll
    for (int k = 0; k < 8; ++k) {
        int i = base + k * 512 + tid;
        if (i < N) atomicAdd(&lh[labels[i]], 1);
    }
    __syncthreads();
    if (tid < 256) { int v = h[tid]; if (v) atomicAdd(&bcnt[tid], v); }
    if (tid < NT) { int v = lh[tid]; if (v) atomicAdd(&lc[tid], v); }
}

// ------- scan buckets -> boff/gcur, rb[8N]=E; label starts (pad 64) -------
__global__ __launch_bounds__(256) void scan_master(
    const int* __restrict__ bcnt, const int* __restrict__ lc,
    int* __restrict__ boff, int* __restrict__ gcur, int* __restrict__ rb,
    int* __restrict__ lstart, int NB, int N, int E) {
    __shared__ int s[256];
    int tid = threadIdx.x;
    int own = (tid < NB) ? bcnt[tid] : 0;
    s[tid] = own;
    __syncthreads();
    for (int d = 1; d < 256; d <<= 1) {
        int v = (tid >= d) ? s[tid - d] : 0;
        __syncthreads();
        s[tid] += v;
        __syncthreads();
    }
    int excl = s[tid] - own;
    if (tid < NB) { boff[tid] = excl; gcur[tid] = excl; }
    if (tid == 0) {
        boff[NB] = E; rb[(size_t)N * 8] = E;
        int run = 0;
        for (int l = 0; l < NT; ++l) {
            lstart[l] = run;
            run += (lc[l] + 63) & ~63;
        }
    }
}

// ------- node scatter: build iperm (orig -> label-sorted slot) -------
__global__ void scatter_nodes(const int* __restrict__ labels, const int* __restrict__ lstart,
                              int* __restrict__ lcur, int* __restrict__ iperm, int N) {
    int n = blockIdx.x * 256 + threadIdx.x;
    int lab = (n < N) ? labels[n] : -1;
    int lane = threadIdx.x & 63;
    for (int l = 0; l < NT; ++l) {
        unsigned long long m = __ballot(lab == l);
        if (m == 0ull) continue;
        int leader = __builtin_ctzll(m);
        int base = 0;
        if (lane == leader) base = atomicAdd(&lcur[l], (int)__popcll(m));
        base = __shfl(base, leader, 64);
        if (lab == l) {
            int prefix = (int)__popcll(m & ((1ull << lane) - 1ull));
            iperm[n] = lstart[l] + base + prefix;
        }
    }
}

// ================= FUSE_A: scatter_edges + cast_x + cast_w_all =================
// seg 0 [0, nbEB): edge scatter into bucket regions; earr rec: x = slot|(dst&255)<<16, y = w
// seg 1 [nbEB, nbEB+nbX): cast x -> bf16 half-split slot rows
// seg 2 rest: cast W1/W2/W3 -> swizzled bf16 + permuted biases
__global__ __launch_bounds__(512) void fuse_a(
    const int* __restrict__ src, const int* __restrict__ dst, const float* __restrict__ w,
    const int* __restrict__ iperm, int* __restrict__ gcur, uint2* __restrict__ earr, int E,
    const float* __restrict__ x, unsigned short* __restrict__ actLo,
    unsigned short* __restrict__ actHi, int total4,
    const float* __restrict__ W1, const float* __restrict__ W2, const float* __restrict__ W3,
    const float* __restrict__ b1, const float* __restrict__ b2,
    unsigned short* __restrict__ W1b, unsigned short* __restrict__ W2b,
    unsigned short* __restrict__ W3b, float* __restrict__ biasPerm,
    int nbEB, int nbX) {
    int tid = threadIdx.x;
    int blk = (int)blockIdx.x;
    if (blk < nbEB) {
        // ---- edge scatter ----
        __shared__ int h[256];
        __shared__ int basearr[256];
        if (tid < 256) h[tid] = 0;
        __syncthreads();
        int base = blk * 4096;
        int b[8], rank[8], px[8]; float wv[8];
#pragma unroll
        for (int k = 0; k < 8; ++k) {
            int e = base + k * 512 + tid;
            if (e < E) {
                int d = dst[e];
                b[k] = ((unsigned)d) >> 8;
                px[k] = iperm[src[e]] | ((d & 255) << 16);
                wv[k] = w[e];
                rank[k] = atomicAdd(&h[b[k]], 1);
            } else b[k] = -1;
        }
        __syncthreads();
        if (tid < 256) { int c = h[tid]; basearr[tid] = c ? atomicAdd(&gcur[tid], c) : 0; }
        __syncthreads();
#pragma unroll
        for (int k = 0; k < 8; ++k) {
            if (b[k] >= 0) {
                int pos = basearr[b[k]] + rank[k];
                earr[pos] = make_uint2((unsigned)px[k], __float_as_uint(wv[k]));
            }
        }
    } else if (blk < nbEB + nbX) {
        // ---- cast x ----
        int i = (blk - nbEB) * 512 + tid;
        if (i < total4) {
            float4 v = ((const float4*)x)[i];
            unsigned int lo = f2bf_bits(v.x) | (f2bf_bits(v.y) << 16);
            unsigned int hi = f2bf_bits(v.z) | (f2bf_bits(v.w) << 16);
            int slot = iperm[i >> 6];
            unsigned short* dp = ((i & 63) >= 32) ? actHi : actLo;
            ((uint2*)dp)[(size_t)slot * 32 + (i & 31)] = make_uint2(lo, hi);
        }
    } else {
        // ---- cast W + biases ----
        const int S = NT * FEAT * FEAT;
        const int S3 = NT * FEAT * OUT3;
        int idx = (blk - nbEB - nbX) * 512 + tid;
        if (idx < 2 * S + S3) {
            const float* W; unsigned short* D; int OUTF; int t; bool remap;
            if (idx < S)          { W = W1; D = W1b; OUTF = FEAT; t = idx;         remap = false; }
            else if (idx < 2 * S) { W = W2; D = W2b; OUTF = FEAT; t = idx - S;     remap = true; }
            else                  { W = W3; D = W3b; OUTF = OUT3; t = idx - 2 * S; remap = true; }
            int n = t % OUTF;
            int r = t / OUTF;              // lab*256 + k_slot
            int j = r & 7, q = (r >> 3) & 3, k0 = (r >> 5) & 7, lab = r >> 8;
            int k_slot = k0 * 32 + q * 8 + j;
            int k_src = remap ? nat_of(k_slot) : k_slot;
            float f = W[((size_t)(lab * FEAT + k_src)) * OUTF + n];
            D[(((size_t)lab * 8 + k0) * OUTF + n) * 32 + q * 8 + j] = (unsigned short)f2bf_bits(f);
        } else {
            int p2 = idx - (2 * S + S3);
            if (p2 < 256) biasPerm[p2] = b1[nat_of(p2)];
            else if (p2 < 512) biasPerm[p2] = b2[nat_of(p2 - 256)];
        }
    }
}

// ------- bucket sort body (256 thr): 2048-bin counting sort by (dst_low8, src_band3) -----
// final record: (w_bf16 << 16) | src_slot. Rows contiguous, band-ascending within row
// (free intra-row phasing for the sequential walk). rb[node*8+k] = band starts.
__device__ void bucket_sort_body(int b, const uint2* __restrict__ earr,
                                 const int* __restrict__ boff, int* __restrict__ rb,
                                 unsigned int* __restrict__ edata, int N) {
    int s = boff[b], e = boff[b + 1];
    __shared__ int cnt[2048], off[2048], ts[256];
    int tid = threadIdx.x;
#pragma unroll
    for (int k = 0; k < 8; ++k) cnt[tid * 8 + k] = 0;
    __syncthreads();
    for (int i = s + tid; i < e; i += 256) {
        unsigned int xx = earr[i].x;
        int key = (((xx >> 16) & 255) << 3) | ((xx & 0xffffu) >> 13);
        atomicAdd(&cnt[key], 1);
    }
    __syncthreads();
    int run = 0;
#pragma unroll
    for (int k = 0; k < 8; ++k) { off[tid * 8 + k] = run; run += cnt[tid * 8 + k]; }
    ts[tid] = run;
    __syncthreads();
    int own = ts[tid];
    for (int d = 1; d < 256; d <<= 1) {
        int v = (tid >= d) ? ts[tid - d] : 0;
        __syncthreads();
        ts[tid] += v;
        __syncthreads();
    }
    int texcl = ts[tid] - own;
#pragma unroll
    for (int k = 0; k < 8; ++k) off[tid * 8 + k] += texcl;
    __syncthreads();
    int node = b * 256 + tid;
    if (node < N) {
#pragma unroll
        for (int k = 0; k < 8; ++k) rb[(size_t)node * 8 + k] = s + off[tid * 8 + k];
    }
    __syncthreads();
    for (int i = s + tid; i < e; i += 256) {
        uint2 r = earr[i];
        unsigned int xx = r.x;
        int key = (((xx >> 16) & 255) << 3) | ((xx & 0xffffu) >> 13);
        int k = atomicAdd(&off[key], 1);
        edata[s + k] = (f2bf_bits(__uint_as_float(r.y)) << 16) | (xx & 0xffffu);
    }
}

// ------- proj 256-out body: dense 64 slots x 256 outs per block, half-split I/O -------
__device__ void proj256_body(int gb,
                             const unsigned short* __restrict__ actLo,
                             const unsigned short* __restrict__ actHi,
                             const unsigned short* __restrict__ Wswz,
                             const int* __restrict__ lstart,
                             unsigned short* __restrict__ supLo,
                             unsigned short* __restrict__ supHi) {
    int warp = threadIdx.x >> 6;
    int lane = threadIdx.x & 63;
    int m0 = gb * 64;
    int lab = (m0 >= lstart[1]) + (m0 >= lstart[2]) + (m0 >= lstart[3]);
    int q = lane >> 4, c = lane & 15;
    int n0 = warp * 64;

    const unsigned short* aLo = actLo + (size_t)(m0 + c) * 128 + q * 8;
    const unsigned short* aHi = actHi + (size_t)(m0 + c) * 128 + q * 8;
    const unsigned short* bb = Wswz + (size_t)lab * FEAT * 256 + (size_t)(n0 + c) * 32 + q * 8;

    f32x4 acc[4][4] = {};
#pragma unroll
    for (int k0 = 0; k0 < 8; ++k0) {
        const unsigned short* abase = (k0 < 4) ? aLo : aHi;
        int koff = (k0 & 3) * 32;
        bf16x8 a[4];
#pragma unroll
        for (int t = 0; t < 4; ++t) a[t] = *(const bf16x8*)(abase + (size_t)t * 2048 + koff);
        const unsigned short* bk = bb + (size_t)k0 * 32 * 256;
#pragma unroll
        for (int u = 0; u < 4; ++u) {
            bf16x8 bfrag = *(const bf16x8*)(bk + u * 512);
#pragma unroll
            for (int t = 0; t < 4; ++t)
                acc[t][u] = __builtin_amdgcn_mfma_f32_16x16x32_bf16(a[t], bfrag, acc[t][u], 0, 0, 0);
        }
    }
    // pi-store: row = m0+t*16+q*4+r ; lane writes p = n0 + c*4 + u -> half n0>>7
    uint2* ov = (uint2*)((n0 >= 128) ? supHi : supLo);
    int cix = ((n0 & 64) >> 2) + c;
#pragma unroll
    for (int t = 0; t < 4; ++t) {
#pragma unroll
        for (int r = 0; r < 4; ++r) {
            int row = m0 + t * 16 + q * 4 + r;
            unsigned int lo = f2bf_bits(acc[t][0][r]) | (f2bf_bits(acc[t][1][r]) << 16);
            unsigned int hi = f2bf_bits(acc[t][2][r]) | (f2bf_bits(acc[t][3][r]) << 16);
            ov[(size_t)row * 32 + cix] = make_uint2(lo, hi);
        }
    }
}

// ================= FUSE_B: bucket_sort (blocks [0,NB)) + proj256 L1 (rest) =================
__global__ __launch_bounds__(256) void fuse_b(
    const uint2* __restrict__ earr, const int* __restrict__ boff,
    int* __restrict__ rb, unsigned int* __restrict__ edata, int N, int NB,
    const unsigned short* __restrict__ actLo, const unsigned short* __restrict__ actHi,
    const unsigned short* __restrict__ Wswz, const int* __restrict__ lstart,
    unsigned short* __restrict__ supLo, unsigned short* __restrict__ supHi) {
    int blk = (int)blockIdx.x;
    if (blk < NB) bucket_sort_body(blk, earr, boff, rb, edata, N);
    else proj256_body(blk - NB, actLo, actHi, Wswz, lstart, supLo, supHi);
}

// ---------------- standalone proj 256 (layer 2) ----------------
__global__ __launch_bounds__(256) void proj256_kernel(
    const unsigned short* __restrict__ actLo, const unsigned short* __restrict__ actHi,
    const unsigned short* __restrict__ Wswz, const int* __restrict__ lstart,
    unsigned short* __restrict__ supLo, unsigned short* __restrict__ supHi) {
    proj256_body((int)blockIdx.x, actLo, actHi, Wswz, lstart, supLo, supHi);
}

// ---------------- proj 64-out: dense 64 slots x 64 outs per block, half-split input ------
__global__ __launch_bounds__(256) void proj64_kernel(
    const unsigned short* __restrict__ actLo, const unsigned short* __restrict__ actHi,
    const unsigned short* __restrict__ Wswz, const int* __restrict__ lstart,
    unsigned short* __restrict__ outp) {
    int warp = threadIdx.x >> 6;
    int lane = threadIdx.x & 63;
    int m0 = blockIdx.x * 64;
    int lab = (m0 >= lstart[1]) + (m0 >= lstart[2]) + (m0 >= lstart[3]);
    int q = lane >> 4, c = lane & 15;
    int mb = m0 + warp * 16;

    const unsigned short* aLo = actLo + (size_t)(mb + c) * 128 + q * 8;
    const unsigned short* aHi = actHi + (size_t)(mb + c) * 128 + q * 8;
    const unsigned short* bb = Wswz + (size_t)lab * FEAT * OUT3 + (size_t)c * 32 + q * 8;

    f32x4 acc[4] = {};
#pragma unroll
    for (int k0 = 0; k0 < 8; ++k0) {
        const unsigned short* abase = (k0 < 4) ? aLo : aHi;
        bf16x8 a = *(const bf16x8*)(abase + (k0 & 3) * 32);
        const unsigned short* bk = bb + (size_t)k0 * 32 * OUT3;
#pragma unroll
        for (int u = 0; u < 4; ++u) {
            bf16x8 bfrag = *(const bf16x8*)(bk + u * 512);
            acc[u] = __builtin_amdgcn_mfma_f32_16x16x32_bf16(a, bfrag, acc[u], 0, 0, 0);
        }
    }
    uint2* ov = (uint2*)outp;
#pragma unroll
    for (int r = 0; r < 4; ++r) {
        int row = mb + q * 4 + r;
        unsigned int lo = f2bf_bits(acc[0][r]) | (f2bf_bits(acc[1][r]) << 16);
        unsigned int hi = f2bf_bits(acc[2][r]) | (f2bf_bits(acc[3][r]) << 16);
        ov[(size_t)row * 16 + c] = make_uint2(lo, hi);
    }
}

// ------- XCD-parity half-split aggregation (128 feats per block) -------
// Block parity selects the feature half; round-robin blockIdx->XCD dispatch then puts
// Lo on even XCDs and Hi on odd XCDs, halving each XCD's compulsory L2-miss traffic
// (each L2 sweeps one 12.8MB half instead of both). Body = proven batch-16 walk;
// edata is band-sorted within each row so co-progressing waves share a src window.
__global__ __launch_bounds__(256) void agg256x_kernel(
    const unsigned int* __restrict__ supLo, const unsigned int* __restrict__ supHi,
    const int* __restrict__ rb, const unsigned int* __restrict__ edata,
    const int* __restrict__ iperm, const float* __restrict__ biasPerm, int bOff,
    unsigned int* __restrict__ outLo, unsigned int* __restrict__ outHi, int N) {
    int blk = (int)blockIdx.x;
    int half = blk & 1;
    int warp = __builtin_amdgcn_readfirstlane((int)(threadIdx.x >> 6));
    int node = (blk >> 1) * 4 + warp;
    if (node >= N) return;
    int lane = threadIdx.x & 63;
    const unsigned int* sup = half ? supHi : supLo;
    unsigned int* outp = half ? outHi : outLo;
    int s = __builtin_amdgcn_readfirstlane(rb[(size_t)node * 8]);
    int e = __builtin_amdgcn_readfirstlane(rb[(size_t)node * 8 + 8]);
    int slot = __builtin_amdgcn_readfirstlane(iperm[node]);
    float a0 = 0.f, a1 = 0.f;
    int j = s;
    for (; j + 16 <= e; j += 16) {
        unsigned int ed[16], v[16];
#pragma unroll
        for (int u = 0; u < 16; ++u) ed[u] = edata[j + u];
        __builtin_amdgcn_sched_barrier(0);
#pragma unroll
        for (int u = 0; u < 16; ++u) v[u] = sup[(size_t)(ed[u] & 0xffff) * 64 + lane];
        __builtin_amdgcn_sched_barrier(0);
#pragma unroll
        for (int u = 0; u < 16; ++u) {
            float w = __uint_as_float(ed[u] & 0xffff0000u);
            a0 += w * bfl(v[u]); a1 += w * bfh(v[u]);
        }
    }
    if (j < e) {   // masked tail (<=15 real edges)
        unsigned int ed[16], v[16]; float wm[16];
#pragma unroll
        for (int u = 0; u < 16; ++u) {
            int jj = j + u;
            int jc = (jj < e) ? jj : e - 1;
            ed[u] = edata[jc];
            wm[u] = (jj < e) ? __uint_as_float(ed[u] & 0xffff0000u) : 0.f;
        }
        __builtin_amdgcn_sched_barrier(0);
#pragma unroll
        for (int u = 0; u < 16; ++u) v[u] = sup[(size_t)(ed[u] & 0xffff) * 64 + lane];
        __builtin_amdgcn_sched_barrier(0);
#pragma unroll
        for (int u = 0; u < 16; ++u) { a0 += wm[u] * bfl(v[u]); a1 += wm[u] * bfh(v[u]); }
    }
    float2 b = ((const float2*)(biasPerm + bOff + half * 128))[lane];
    a0 = fmaxf(a0 + b.x, 0.f);
    a1 = fmaxf(a1 + b.y, 0.f);
    unsigned int o = f2bf_bits(a0) | (f2bf_bits(a1) << 16);
    // output never re-read here: nontemporal keeps the sup window resident in L2
    __builtin_nontemporal_store(o, &outp[(size_t)slot * 64 + lane]);
}

// ---------------- aggregation, 64-feat: one wave per node (lane = stored pos), fp32 out --
__global__ __launch_bounds__(256) void agg64_kernel(
    const unsigned short* __restrict__ sup, const int* __restrict__ rb,
    const unsigned int* __restrict__ edata, const float* __restrict__ b3,
    float* __restrict__ outp, int N) {
    int warp = __builtin_amdgcn_readfirstlane((int)(threadIdx.x >> 6));
    int node = (int)blockIdx.x * 4 + warp;
    if (node >= N) return;
    int lane = threadIdx.x & 63;
    int s = __builtin_amdgcn_readfirstlane(rb[(size_t)node * 8]);
    int e = __builtin_amdgcn_readfirstlane(rb[(size_t)node * 8 + 8]);
    float a = 0.f;
    int j = s;
    for (; j + 16 <= e; j += 16) {
        unsigned int ed[16]; unsigned short v[16];
#pragma unroll
        for (int u = 0; u < 16; ++u) ed[u] = edata[j + u];
#pragma unroll
        for (int u = 0; u < 16; ++u) v[u] = sup[(size_t)(ed[u] & 0xffff) * 64 + lane];
#pragma unroll
        for (int u = 0; u < 16; ++u)
            a += __uint_as_float(ed[u] & 0xffff0000u) * __uint_as_float((unsigned int)v[u] << 16);
    }
    if (j < e) {
        unsigned int ed[16]; float wm[16]; unsigned short v[16];
#pragma unroll
        for (int u = 0; u < 16; ++u) {
            int jj = j + u;
            int jc = (jj < e) ? jj : e - 1;
            ed[u] = edata[jc];
            wm[u] = (jj < e) ? __uint_as_float(ed[u] & 0xffff0000u) : 0.f;
        }
#pragma unroll
        for (int u = 0; u < 16; ++u) v[u] = sup[(size_t)(ed[u] & 0xffff) * 64 + lane];
#pragma unroll
        for (int u = 0; u < 16; ++u)
            a += wm[u] * __uint_as_float((unsigned int)v[u] << 16);
    }
    int natp = (((lane & 3) << 4) | (lane >> 2));    // un-permute pi within the 64 outs
    outp[(size_t)node * 64 + natp] = a + b3[natp];
}

extern "C" void kernel_launch(void* const* d_in, const int* in_sizes, int n_in,
                              void* d_out, int out_size, void* d_ws, size_t ws_size,
                              hipStream_t stream) {
    const float* x        = (const float*)d_in[0];
    const int*   edge_src = (const int*)d_in[1];
    const int*   edge_dst = (const int*)d_in[2];
    const float* edge_w   = (const float*)d_in[3];
    const int*   labels   = (const int*)d_in[4];
    const float* W1 = (const float*)d_in[5];
    const float* b1 = (const float*)d_in[6];
    const float* W2 = (const float*)d_in[7];
    const float* b2 = (const float*)d_in[8];
    const float* W3 = (const float*)d_in[9];
    const float* b3 = (const float*)d_in[10];

    const int N = in_sizes[0] / FEAT;
    const int E = in_sizes[1];
    const int NB = (N + 255) >> 8;                    // dst buckets (orig id space)
    const int G64 = (N + NT * 64 + 63) / 64;          // slot-space 64-row tiles (upper bound)
    const int slotCap = G64 * 64;

    // ---- workspace carve (256B aligned) ----
    char* p = (char*)d_ws;
    auto alloc = [&](size_t bytes) -> char* {
        char* r = p;
        p += (bytes + 255) & ~(size_t)255;
        return r;
    };
    unsigned short* bufA = (unsigned short*)alloc((size_t)slotCap * FEAT * 2);
    unsigned short* bufB = (unsigned short*)alloc((size_t)slotCap * FEAT * 2);
    unsigned short* W1b  = (unsigned short*)alloc((size_t)NT * FEAT * FEAT * 2);
    unsigned short* W2b  = (unsigned short*)alloc((size_t)NT * FEAT * FEAT * 2);
    unsigned short* W3b  = (unsigned short*)alloc((size_t)NT * FEAT * OUT3 * 2);
    float*        biasPerm = (float*)alloc(512 * 4);
    int*          rb     = (int*)alloc(((size_t)N * 8 + 8) * 4);
    unsigned int* edata  = (unsigned int*)alloc((size_t)E * 4);
    int*          iperm  = (int*)alloc((size_t)N * 4);
    int*          counters = (int*)alloc(264 * 4);    // bcnt[256] + lc[4] + lcur[4]
    int*          boff   = (int*)alloc(257 * 4);
    int*          gcur   = (int*)alloc(256 * 4);
    int*          lstart = (int*)alloc(64);
    int* bcnt = counters;
    int* lc   = counters + 256;
    int* lcur = counters + 260;

    // half-table views (lo = feats p<128, hi = p>=128), each slotCap*128 ushorts
    unsigned short* actLo = bufA;
    unsigned short* actHi = bufA + (size_t)slotCap * 128;
    unsigned short* supLo = bufB;
    unsigned short* supHi = bufB + (size_t)slotCap * 128;
    // bucket-sort staging ALIASED onto d_out (N*OUT3*4 = 12.8MB = E*8; d_out written
    // only by the final agg64, and earr is fully overwritten by scatter before reads)
    uint2* earr = (uint2*)d_out;

    const int nbEB = (E + 4095) / 4096;
    const int total4 = N * 64;                        // float4 groups in x
    const int nbX = (total4 + 511) / 512;
    const int totW = 2 * NT * FEAT * FEAT + NT * FEAT * OUT3 + 512;
    const int nbW = (totW + 511) / 512;

    // ---- CSR build + label-sort + casts ----
    hipMemsetAsync(counters, 0, 264 * 4, stream);
    pass_a<<<nbEB, 512, 0, stream>>>(edge_dst, labels, bcnt, lc, E, N);
    scan_master<<<1, 256, 0, stream>>>(bcnt, lc, boff, gcur, rb, lstart, NB, N, E);
    scatter_nodes<<<(N + 255) / 256, 256, 0, stream>>>(labels, lstart, lcur, iperm, N);
    fuse_a<<<nbEB + nbX + nbW, 512, 0, stream>>>(
        edge_src, edge_dst, edge_w, iperm, gcur, earr, E,
        x, actLo, actHi, total4,
        W1, W2, W3, b1, b2, W1b, W2b, W3b, biasPerm, nbEB, nbX);

    const int aggGrid = (N + 3) / 4;
    // ---- layer 1 (band sort overlapped with proj256-L1) ----
    fuse_b<<<NB + G64, 256, 0, stream>>>(earr, boff, rb, edata, N, NB,
                                         actLo, actHi, W1b, lstart, supLo, supHi);
    agg256x_kernel<<<2 * aggGrid, 256, 0, stream>>>(
        (const unsigned int*)supLo, (const unsigned int*)supHi, rb, edata, iperm,
        biasPerm, 0, (unsigned int*)actLo, (unsigned int*)actHi, N);
    // ---- layer 2 ----
    proj256_kernel<<<G64, 256, 0, stream>>>(actLo, actHi, W2b, lstart, supLo, supHi);
    agg256x_kernel<<<2 * aggGrid, 256, 0, stream>>>(
        (const unsigned int*)supLo, (const unsigned int*)supHi, rb, edata, iperm,
        biasPerm, 256, (unsigned int*)actLo, (unsigned int*)actHi, N);
    // ---- layer 3 ----
    proj64_kernel<<<G64, 256, 0, stream>>>(actLo, actHi, W3b, lstart, bufB);
    agg64_kernel<<<aggGrid, 256, 0, stream>>>(bufB, rb, edata, b3, (float*)d_out, N);
}